// Round 7
// baseline (179.840 us; speedup 1.0000x reference)
//
#include <hip/hip_runtime.h>

// Problem: B=2, S=2048, D=1024, H=16, hd=64. fp32 in/out; internal bf16 MFMA.
#define S_LEN 2048
#define DIM   1024
#define NHEAD 16
#define HDIM  64
#define Q_PRESCALE 0.045084220027780106f   // log2(e)/sqrt(D): exp2 softmax

typedef __attribute__((ext_vector_type(8))) short  short8;   // 8 bf16
typedef __attribute__((ext_vector_type(4))) float  floatx4;  // MFMA C/D
typedef __attribute__((ext_vector_type(4))) unsigned short ushort4v;
typedef __attribute__((ext_vector_type(4))) unsigned int uintx4;

__device__ inline unsigned short f2bf(float f) {
  unsigned v = __builtin_bit_cast(unsigned, f);
  v += 0x7FFFu + ((v >> 16) & 1u);   // RTNE
  return (unsigned short)(v >> 16);
}

// pack two f32 -> one dword of 2 bf16 (lo=a, hi=b), RTNE
__device__ inline unsigned cvt_pk_bf16(float a, float b) {
  unsigned r;
  asm("v_cvt_pk_bf16_f32 %0, %1, %2" : "=v"(r) : "v"(a), "v"(b));
  return r;
}

// v_permlane16_swap_b32: a.lanes[16..31] <-> b.lanes[0..15] (per 32-lane half)
__device__ inline void permlane16_swap_rw(unsigned &a, unsigned &b) {
  asm("v_permlane16_swap_b32 %0, %1" : "+v"(a), "+v"(b));
}

// async global->LDS, 16B/lane; LDS dest = wave-uniform base + lane*16.
__device__ inline void async16(const unsigned short* g, unsigned short* l) {
  __builtin_amdgcn_global_load_lds(
      (const __attribute__((address_space(1))) unsigned int*)g,
      (__attribute__((address_space(3))) unsigned int*)l, 16, 0, 0);
}

// ---- prep: W transposes (+cvt) and optional X cvt, ONE launch ----
__global__ __launch_bounds__(256) void prep_kernel(
    const float* __restrict__ X, const float* __restrict__ Wqkv,
    const float* __restrict__ Wout, unsigned short* __restrict__ Xb,
    unsigned short* __restrict__ Wqkvt, unsigned short* __restrict__ Woutt) {
  const int j = blockIdx.x, t = threadIdx.x;
  if (j >= 4096) {
    int i = ((j - 4096) * 256 + t) * 8;
    float4 a = *(const float4*)&X[i];
    float4 b = *(const float4*)&X[i + 4];
    short8 o;
    o[0] = (short)f2bf(a.x); o[1] = (short)f2bf(a.y);
    o[2] = (short)f2bf(a.z); o[3] = (short)f2bf(a.w);
    o[4] = (short)f2bf(b.x); o[5] = (short)f2bf(b.y);
    o[6] = (short)f2bf(b.z); o[7] = (short)f2bf(b.w);
    *(short8*)&Xb[i] = o;
    return;
  }
  __shared__ unsigned short tile[32][33];
  const float* in; unsigned short* out; int N, tn, tk;
  if (j < 3072) { in = Wqkv; out = Wqkvt; N = 3072; tn = j % 96; tk = j / 96; }
  else { int u = j - 3072; in = Wout; out = Woutt; N = 1024; tn = u & 31; tk = u >> 5; }
  const int n0 = tn * 32, k0 = tk * 32;
  const int tx = t & 31, ty = t >> 5;   // 32 x 8
#pragma unroll
  for (int i = 0; i < 32; i += 8)
    tile[ty + i][tx] = f2bf(in[(size_t)(k0 + ty + i) * N + n0 + tx]);
  __syncthreads();
#pragma unroll
  for (int i = 0; i < 32; i += 8)
    out[(size_t)(n0 + ty + i) * 1024 + k0 + tx] = tile[tx][ty + i];
}

// ================= 128x128-tile MFMA GEMM core (m97 structure) =================
#define GEMM128_BODY(APTR, BPTR)                                                   \
  __shared__ __align__(16) unsigned short As[128][64];                             \
  __shared__ __align__(16) unsigned short Bs[128][64];                             \
  const int m0 = blockIdx.y * 128, n0 = blockIdx.x * 128;                          \
  const int t = threadIdx.x, lane = t & 63, wave = t >> 6;                         \
  const int quad = lane >> 4, l16 = lane & 15;                                     \
  const int wm = (wave >> 1) * 64, wn = (wave & 1) * 64;                           \
  const int lr = lane >> 3, lc = lane & 7, sc8 = (lc ^ lr) * 8;                    \
  const int sw = l16 & 7;                                                          \
  const int pA0 = (quad ^ sw) * 8, pA1 = ((4 + quad) ^ sw) * 8;                    \
  floatx4 acc[4][4];                                                               \
  _Pragma("unroll") for (int mi = 0; mi < 4; mi++)                                 \
      _Pragma("unroll") for (int ni = 0; ni < 4; ni++)                             \
          acc[mi][ni] = (floatx4){0.f, 0.f, 0.f, 0.f};                             \
  for (int k0 = 0; k0 < DIM; k0 += 64) {                                           \
    _Pragma("unroll") for (int i = 0; i < 4; i++) {                                \
      int rb = wave * 32 + i * 8;                                                  \
      async16(&APTR[(size_t)(m0 + rb + lr) * DIM + k0 + sc8], &As[rb][0]);         \
      async16(&BPTR[(size_t)(n0 + rb + lr) * DIM + k0 + sc8], &Bs[rb][0]);         \
    }                                                                              \
    __syncthreads();                                                               \
    short8 a0[4], a1[4];                                                           \
    _Pragma("unroll") for (int mi = 0; mi < 4; mi++) {                             \
      int row = wm + mi * 16 + l16;                                                \
      a0[mi] = *(const short8*)&As[row][pA0];                                      \
      a1[mi] = *(const short8*)&As[row][pA1];                                      \
    }                                                                              \
    _Pragma("unroll") for (int ni = 0; ni < 4; ni++) {                             \
      int row = wn + ni * 16 + l16;                                                \
      short8 b0 = *(const short8*)&Bs[row][pA0];                                   \
      short8 b1 = *(const short8*)&Bs[row][pA1];                                   \
      _Pragma("unroll") for (int mi = 0; mi < 4; mi++) {                           \
        acc[mi][ni] = __builtin_amdgcn_mfma_f32_16x16x32_bf16(a0[mi], b0, acc[mi][ni], 0, 0, 0); \
        acc[mi][ni] = __builtin_amdgcn_mfma_f32_16x16x32_bf16(a1[mi], b1, acc[mi][ni], 0, 0, 0); \
      }                                                                            \
    }                                                                              \
    __syncthreads();                                                               \
  }

// ---- GEMM1: qkv = Xb @ Wqkvt^T + b; scatter Q^T(prescaled)/K/V^T ----
// Q now stored TRANSPOSED [y][hd][s] like V -> ushort4v stores (was 64 scalar).
__global__ __launch_bounds__(256) void gemm_qkv128(
    const unsigned short* __restrict__ Xb,
    const unsigned short* __restrict__ Wt,
    const float* __restrict__ bias,
    unsigned short* __restrict__ Qgt,
    unsigned short* __restrict__ Kg,
    unsigned short* __restrict__ Vgt) {
  GEMM128_BODY(Xb, Wt)
  const int section = n0 >> 10;
  const int head = ((n0 + wn) >> 6) & 15;
#pragma unroll
  for (int mi = 0; mi < 4; mi++) {
    int mg = m0 + wm + mi * 16 + quad * 4;
    int bb = mg >> 11, sb = mg & 2047;
    size_t y = (size_t)bb * NHEAD + head;
    if (section == 2) {
#pragma unroll
      for (int ni = 0; ni < 4; ni++) {
        int hdi = ni * 16 + l16;
        float bv = bias[n0 + wn + hdi];
        ushort4v o;
#pragma unroll
        for (int r = 0; r < 4; r++) o[r] = f2bf(acc[mi][ni][r] + bv);
        *(ushort4v*)&Vgt[(y * HDIM + hdi) * S_LEN + sb] = o;
      }
    } else if (section == 0) {
#pragma unroll
      for (int ni = 0; ni < 4; ni++) {
        int hdi = ni * 16 + l16;
        float bv = bias[n0 + wn + hdi];
        ushort4v o;
#pragma unroll
        for (int r = 0; r < 4; r++) o[r] = f2bf((acc[mi][ni][r] + bv) * Q_PRESCALE);
        *(ushort4v*)&Qgt[(y * HDIM + hdi) * S_LEN + sb] = o;
      }
    } else {
#pragma unroll
      for (int ni = 0; ni < 4; ni++) {
        int hdi = ni * 16 + l16;
        float bv = bias[n0 + wn + hdi];
#pragma unroll
        for (int r = 0; r < 4; r++)
          Kg[(y * S_LEN + sb + r) * HDIM + hdi] = f2bf(acc[mi][ni][r] + bv);
      }
    }
  }
}

// ---- GEMM2: out = attnB @ Woutt^T + b (fp32 out) ----
// 64x64 tile, 128-thread blocks, grid (16,64) = 1024 blocks (~4/CU).
__global__ __launch_bounds__(128) void gemm_out64(
    const unsigned short* __restrict__ A,
    const unsigned short* __restrict__ Wt,
    const float* __restrict__ bias,
    float* __restrict__ outp) {
  __shared__ __align__(16) unsigned short As[64][64];
  __shared__ __align__(16) unsigned short Bs[64][64];
  const int m0 = blockIdx.y * 64, n0 = blockIdx.x * 64;
  const int t = threadIdx.x, lane = t & 63, wave = t >> 6;   // wave 0..1
  const int quad = lane >> 4, l16 = lane & 15;
  const int wn = wave * 32;
  const int lr = lane >> 3, lc = lane & 7, sc8 = (lc ^ lr) * 8;
  const int sw = l16 & 7;
  const int pA0 = (quad ^ sw) * 8, pA1 = ((4 + quad) ^ sw) * 8;
  floatx4 acc[4][2];
#pragma unroll
  for (int mi = 0; mi < 4; mi++)
#pragma unroll
    for (int ni = 0; ni < 2; ni++) acc[mi][ni] = (floatx4){0.f, 0.f, 0.f, 0.f};

  for (int k0 = 0; k0 < DIM; k0 += 64) {
#pragma unroll
    for (int i = 0; i < 4; i++) {                 // A,B: 64 rows each, 32/wave
      int rb = wave * 32 + i * 8;
      async16(&A[(size_t)(m0 + rb + lr) * DIM + k0 + sc8], &As[rb][0]);
      async16(&Wt[(size_t)(n0 + rb + lr) * DIM + k0 + sc8], &Bs[rb][0]);
    }
    __syncthreads();
    short8 a0[4], a1[4];
#pragma unroll
    for (int mi = 0; mi < 4; mi++) {
      int row = mi * 16 + l16;
      a0[mi] = *(const short8*)&As[row][pA0];
      a1[mi] = *(const short8*)&As[row][pA1];
    }
#pragma unroll
    for (int ni = 0; ni < 2; ni++) {
      int row = wn + ni * 16 + l16;
      short8 b0 = *(const short8*)&Bs[row][pA0];
      short8 b1 = *(const short8*)&Bs[row][pA1];
#pragma unroll
      for (int mi = 0; mi < 4; mi++) {
        acc[mi][ni] = __builtin_amdgcn_mfma_f32_16x16x32_bf16(a0[mi], b0, acc[mi][ni], 0, 0, 0);
        acc[mi][ni] = __builtin_amdgcn_mfma_f32_16x16x32_bf16(a1[mi], b1, acc[mi][ni], 0, 0, 0);
      }
    }
    __syncthreads();
  }
#pragma unroll
  for (int ni = 0; ni < 2; ni++) {
    int n = n0 + wn + ni * 16 + l16;
    float bv = bias[n];
#pragma unroll
    for (int mi = 0; mi < 4; mi++) {
      int mg = m0 + mi * 16 + quad * 4;
#pragma unroll
      for (int r = 0; r < 4; r++)
        outp[(size_t)(mg + r) * DIM + n] = acc[mi][ni][r] + bv;
    }
  }
}

// ---- fallback GEMM1 (64-tile, inline X convert) for ws_size < 48 MiB ----
__global__ __launch_bounds__(256) void gemm_qkv_kernel(
    const float* __restrict__ X,
    const unsigned short* __restrict__ Wt,
    const float* __restrict__ bias,
    unsigned short* __restrict__ Qgt,
    unsigned short* __restrict__ Kg,
    unsigned short* __restrict__ Vgt,
    int g0, int G) {
  __shared__ __align__(16) unsigned short As[64][72];
  __shared__ __align__(16) unsigned short Bs[64][72];
  const int tn = blockIdx.x;
  const int section = tn / G, within = tn % G;
  const int n0 = section * 1024 + (g0 + within) * 64;
  const int m0 = blockIdx.y * 64;
  const int t = threadIdx.x, lane = t & 63, wave = t >> 6;
  const int quad = lane >> 4, l16 = lane & 15;

  floatx4 acc[4];
#pragma unroll
  for (int i = 0; i < 4; i++) acc[i] = (floatx4){0.f, 0.f, 0.f, 0.f};

  for (int k0 = 0; k0 < DIM; k0 += 64) {
#pragma unroll
    for (int i = 0; i < 2; i++) {
      int v = t + i * 256;
      int row = v >> 3, cc = (v & 7) * 8;
      float4 f0 = *(const float4*)&X[(size_t)(m0 + row) * DIM + k0 + cc];
      float4 f1 = *(const float4*)&X[(size_t)(m0 + row) * DIM + k0 + cc + 4];
      short8 o;
      o[0] = (short)f2bf(f0.x); o[1] = (short)f2bf(f0.y);
      o[2] = (short)f2bf(f0.z); o[3] = (short)f2bf(f0.w);
      o[4] = (short)f2bf(f1.x); o[5] = (short)f2bf(f1.y);
      o[6] = (short)f2bf(f1.z); o[7] = (short)f2bf(f1.w);
      *(short8*)&As[row][cc] = o;
      *(short8*)&Bs[row][cc] = *(const short8*)&Wt[(size_t)(n0 + row) * DIM + k0 + cc];
    }
    __syncthreads();
    short8 a0 = *(const short8*)&As[wave * 16 + l16][quad * 8];
    short8 a1 = *(const short8*)&As[wave * 16 + l16][32 + quad * 8];
#pragma unroll
    for (int nt = 0; nt < 4; nt++) {
      short8 b0 = *(const short8*)&Bs[nt * 16 + l16][quad * 8];
      short8 b1 = *(const short8*)&Bs[nt * 16 + l16][32 + quad * 8];
      acc[nt] = __builtin_amdgcn_mfma_f32_16x16x32_bf16(a0, b0, acc[nt], 0, 0, 0);
      acc[nt] = __builtin_amdgcn_mfma_f32_16x16x32_bf16(a1, b1, acc[nt], 0, 0, 0);
    }
    __syncthreads();
  }

  const int mbase = m0 + wave * 16 + quad * 4;
  const int b = mbase >> 11, sbase = mbase & 2047;
  const int y = b * G + within;
  if (section == 2) {
#pragma unroll
    for (int nt = 0; nt < 4; nt++) {
      int hdi = nt * 16 + l16;
      float bv = bias[n0 + hdi];
      ushort4v o;
#pragma unroll
      for (int r = 0; r < 4; r++) o[r] = f2bf(acc[nt][r] + bv);
      *(ushort4v*)&Vgt[((size_t)y * HDIM + hdi) * S_LEN + sbase] = o;
    }
  } else if (section == 0) {
#pragma unroll
    for (int nt = 0; nt < 4; nt++) {
      int hdi = nt * 16 + l16;
      float bv = bias[n0 + hdi];
      ushort4v o;
#pragma unroll
      for (int r = 0; r < 4; r++) o[r] = f2bf((acc[nt][r] + bv) * Q_PRESCALE);
      *(ushort4v*)&Qgt[((size_t)y * HDIM + hdi) * S_LEN + sbase] = o;
    }
  } else {
#pragma unroll
    for (int nt = 0; nt < 4; nt++) {
      int hdi = nt * 16 + l16;
      float bv = bias[n0 + hdi];
#pragma unroll
      for (int r = 0; r < 4; r++)
        Kg[((size_t)y * S_LEN + sbase + r) * HDIM + hdi] = f2bf(acc[nt][r] + bv);
    }
  }
}

// ---- attention v10: v9 + T15 2-deep PV pipeline (V triple-buffered) ----
// PV(t-1) issued while softmax(t) runs: MFMA pipe overlaps VALU pipe.
// V slots rotate mod 3; hazard audit: write slot (t+1)%3 never equals
// PV-read slot (t-1)%3; K stays double-buffered (read at t, overwritten t+1).
// Q is now TRANSPOSED [y][hd][s]: 16 one-time scalar loads per block.
__global__ __launch_bounds__(256) void attn_kernel(
    const unsigned short* __restrict__ Qgt,
    const unsigned short* __restrict__ Kg,
    const unsigned short* __restrict__ Vgt,
    unsigned short* __restrict__ attnB) {
  __shared__ __align__(16) unsigned short Ks[2][64][64];   // [buf][key][hd], XOR-swizzled
  __shared__ __align__(16) unsigned short Vs[3][64][64];   // [slot][hd][key], XOR-swizzled

  const int y = blockIdx.x;                // 0..31 (b,h)
  const int b = y >> 4, h = y & 15;
  const int qt = 31 - blockIdx.y;          // heavy-first
  const int q0 = qt * 64;
  const int nT = qt + 1;
  const int t = threadIdx.x;
  const int lane = t & 63, wave = t >> 6;
  const int quad = lane >> 4, l16 = lane & 15;
  const int lr = lane >> 3, lc = lane & 7;
  const int sc8 = (lc ^ lr) * 8;
  const int sw = l16 & 7;
  const int p0 = (quad ^ sw) * 8, p1 = ((4 + quad) ^ sw) * 8;

  const unsigned short* Qh = Qgt + (size_t)y * S_LEN * HDIM;   // [hd][s]
  const unsigned short* Kh = Kg + (size_t)y * S_LEN * HDIM;    // [s][hd]
  const unsigned short* Vh = Vgt + (size_t)y * HDIM * S_LEN;   // [hd][s]

  // constant Ones B-fragment: B[n][k] = (n==0) ? 1 : 0  -> row-sum in col 0
  const unsigned ov = (l16 == 0) ? 0x3F803F80u : 0u;
  const uintx4 ou = {ov, ov, ov, ov};
  const short8 ones = __builtin_bit_cast(short8, ou);

  // Q fragment from transposed layout: aq0[j] = Q[hd=quad*8+j][s=q0+wave*16+l16]
  short8 aq0, aq1;
  {
    const int s = q0 + wave * 16 + l16;
#pragma unroll
    for (int j = 0; j < 8; j++) {
      aq0[j] = (short)Qh[(size_t)(quad * 8 + j) * S_LEN + s];
      aq1[j] = (short)Qh[(size_t)(32 + quad * 8 + j) * S_LEN + s];
    }
  }

  floatx4 o_acc[5];
#pragma unroll
  for (int dt = 0; dt < 5; dt++) o_acc[dt] = (floatx4){0.f, 0.f, 0.f, 0.f};

  {
    int rb = wave * 16;
#pragma unroll
    for (int i = 0; i < 2; i++) {
      async16(&Kh[(size_t)(rb + i * 8 + lr) * HDIM + sc8], &Ks[0][rb + i * 8][0]);
      async16(&Vh[(size_t)(rb + i * 8 + lr) * S_LEN + sc8], &Vs[0][rb + i * 8][0]);
    }
  }

  int prevV = 2, curV = 0, nextV = 1;
  short8 apP0, apP1;                       // P frags of tile t-1

  for (int tt = 0; tt < nT; tt++) {
    const int j0 = tt * 64;
    const int kb = tt & 1;
    __syncthreads();
    if (tt + 1 < nT) {
      int j1 = j0 + 64;
      int rb = wave * 16;
#pragma unroll
      for (int i = 0; i < 2; i++) {
        async16(&Kh[(size_t)(j1 + rb + i * 8 + lr) * HDIM + sc8], &Ks[kb ^ 1][rb + i * 8][0]);
        async16(&Vh[(size_t)(rb + i * 8 + lr) * S_LEN + j1 + sc8], &Vs[nextV][rb + i * 8][0]);
      }
    }

    // swapped QK^T: sc[nt][r] = S[key = j0 + nt*16 + quad*4 + r][q = q0 + wave*16 + l16]
    floatx4 sc[4];
#pragma unroll
    for (int nt = 0; nt < 4; nt++) {
      short8 kb0 = *(const short8*)&Ks[kb][nt * 16 + l16][p0];
      short8 kb1 = *(const short8*)&Ks[kb][nt * 16 + l16][p1];
      sc[nt] = (floatx4){0.f, 0.f, 0.f, 0.f};
      sc[nt] = __builtin_amdgcn_mfma_f32_16x16x32_bf16(kb0, aq0, sc[nt], 0, 0, 0);
      sc[nt] = __builtin_amdgcn_mfma_f32_16x16x32_bf16(kb1, aq1, sc[nt], 0, 0, 0);
    }

    // PV(t-1): independent of sc -> overlaps the softmax below on the MFMA pipe
    if (tt > 0) {
#pragma unroll
      for (int dt = 0; dt < 5; dt++) {
        short8 vb0 = (dt < 4) ? *(const short8*)&Vs[prevV][dt * 16 + l16][p0] : ones;
        short8 vb1 = (dt < 4) ? *(const short8*)&Vs[prevV][dt * 16 + l16][p1] : ones;
        o_acc[dt] = __builtin_amdgcn_mfma_f32_16x16x32_bf16(apP0, vb0, o_acc[dt], 0, 0, 0);
        o_acc[dt] = __builtin_amdgcn_mfma_f32_16x16x32_bf16(apP1, vb1, o_acc[dt], 0, 0, 0);
      }
    }

    float p[4][4];
#pragma unroll
    for (int nt = 0; nt < 4; nt++)
#pragma unroll
      for (int r = 0; r < 4; r++)
        p[nt][r] = exp2f(sc[nt][r]);
    if (j0 == q0) {
      const int ql = wave * 16 + l16;
#pragma unroll
      for (int nt = 0; nt < 4; nt++)
#pragma unroll
        for (int r = 0; r < 4; r++)
          if (nt * 16 + quad * 4 + r > ql) p[nt][r] = 0.f;
    }

    // pack r-pairs to bf16 dwords
    unsigned pk00 = cvt_pk_bf16(p[0][0], p[0][1]), pk01 = cvt_pk_bf16(p[0][2], p[0][3]);
    unsigned pk10 = cvt_pk_bf16(p[1][0], p[1][1]), pk11 = cvt_pk_bf16(p[1][2], p[1][3]);
    unsigned pk20 = cvt_pk_bf16(p[2][0], p[2][1]), pk21 = cvt_pk_bf16(p[2][2], p[2][3]);
    unsigned pk30 = cvt_pk_bf16(p[3][0], p[3][1]), pk31 = cvt_pk_bf16(p[3][2], p[3][3]);

    // permlane network -> P frags for NEXT iteration's PV
    auto sa0 = __builtin_amdgcn_permlane32_swap(pk00, pk10, false, false);
    auto sa1 = __builtin_amdgcn_permlane32_swap(pk01, pk11, false, false);
    auto sb0 = __builtin_amdgcn_permlane32_swap(pk20, pk30, false, false);
    auto sb1 = __builtin_amdgcn_permlane32_swap(pk21, pk31, false, false);
    unsigned xa0 = (unsigned)sa0[0], ya0 = (unsigned)sa0[1];
    unsigned xa1 = (unsigned)sa1[0], ya1 = (unsigned)sa1[1];
    unsigned xb0 = (unsigned)sb0[0], yb0 = (unsigned)sb0[1];
    unsigned xb1 = (unsigned)sb1[0], yb1 = (unsigned)sb1[1];
    permlane16_swap_rw(xa0, ya0);
    permlane16_swap_rw(xa1, ya1);
    permlane16_swap_rw(xb0, yb0);
    permlane16_swap_rw(xb1, yb1);
    uintx4 u0 = {xa0, xa1, ya0, ya1};
    apP0 = __builtin_bit_cast(short8, u0);
    uintx4 u1 = {xb0, xb1, yb0, yb1};
    apP1 = __builtin_bit_cast(short8, u1);

    int tmp = prevV; prevV = curV; curV = nextV; nextV = tmp;
  }

  // epilogue: PV(nT-1) from Vs[prevV] (= (nT-1)%3)
#pragma unroll
  for (int dt = 0; dt < 5; dt++) {
    short8 vb0 = (dt < 4) ? *(const short8*)&Vs[prevV][dt * 16 + l16][p0] : ones;
    short8 vb1 = (dt < 4) ? *(const short8*)&Vs[prevV][dt * 16 + l16][p1] : ones;
    o_acc[dt] = __builtin_amdgcn_mfma_f32_16x16x32_bf16(apP0, vb0, o_acc[dt], 0, 0, 0);
    o_acc[dt] = __builtin_amdgcn_mfma_f32_16x16x32_bf16(apP1, vb1, o_acc[dt], 0, 0, 0);
  }

  float linv[4];
#pragma unroll
  for (int r = 0; r < 4; r++)
    linv[r] = 1.0f / __shfl(o_acc[4][r], quad << 4);
#pragma unroll
  for (int dt = 0; dt < 4; dt++)
#pragma unroll
    for (int r = 0; r < 4; r++) {
      int qg = q0 + wave * 16 + quad * 4 + r;
      attnB[(size_t)(b * S_LEN + qg) * DIM + h * HDIM + dt * 16 + l16] =
          f2bf(o_acc[dt][r] * linv[r]);
    }
}

extern "C" void kernel_launch(void* const* d_in, const int* in_sizes, int n_in,
                              void* d_out, int out_size, void* d_ws, size_t ws_size,
                              hipStream_t stream) {
  const float* X    = (const float*)d_in[0];
  const float* Wqkv = (const float*)d_in[1];
  const float* bqkv = (const float*)d_in[2];
  const float* Wout = (const float*)d_in[3];
  const float* bout = (const float*)d_in[4];
  float* outp = (float*)d_out;

  unsigned short* Wqkvt = (unsigned short*)d_ws;
  unsigned short* Woutt = Wqkvt + (size_t)3145728;
  unsigned short* attnB = Woutt + (size_t)1048576;
  unsigned short* Qgt   = attnB + (size_t)4194304;
  unsigned short* Kg    = Qgt + (size_t)4194304;
  unsigned short* Vgt   = Kg + (size_t)4194304;
  unsigned short* Xb    = Vgt + (size_t)4194304;

  const bool bigWs = ws_size >= (size_t)48 * 1024 * 1024;

  if (bigWs) {
    // one prep launch: W transposes (blocks 0..4095) + X cvt (blocks 4096..6143)
    prep_kernel<<<6144, 256, 0, stream>>>(X, Wqkv, Wout, Xb, Wqkvt, Woutt);
    gemm_qkv128<<<dim3(24, 32), 256, 0, stream>>>(Xb, Wqkvt, bqkv, Qgt, Kg, Vgt);
  } else {
    // transposes only (no Xb room); 64-tile gemm converts X inline
    prep_kernel<<<4096, 256, 0, stream>>>(X, Wqkv, Wout, nullptr, Wqkvt, Woutt);
    gemm_qkv_kernel<<<dim3(48, 64), 256, 0, stream>>>(
        X, Wqkvt, bqkv, Qgt, Kg, Vgt, 0, 16);
  }
  attn_kernel<<<dim3(32, 32), 256, 0, stream>>>(Qgt, Kg, Vgt, attnB);
  gemm_out64<<<dim3(16, 64), 128, 0, stream>>>(attnB, Woutt, bout, outp);
}

// Round 8
// 178.807 us; speedup vs baseline: 1.0058x; 1.0058x over previous
//
#include <hip/hip_runtime.h>

// Problem: B=2, S=2048, D=1024, H=16, hd=64. fp32 in/out; internal bf16 MFMA.
#define S_LEN 2048
#define DIM   1024
#define NHEAD 16
#define HDIM  64
#define Q_PRESCALE 0.045084220027780106f   // log2(e)/sqrt(D): exp2 softmax

typedef __attribute__((ext_vector_type(8))) short  short8;   // 8 bf16
typedef __attribute__((ext_vector_type(4))) float  floatx4;  // MFMA C/D
typedef __attribute__((ext_vector_type(4))) unsigned short ushort4v;
typedef __attribute__((ext_vector_type(4))) unsigned int uintx4;

__device__ inline unsigned short f2bf(float f) {
  unsigned v = __builtin_bit_cast(unsigned, f);
  v += 0x7FFFu + ((v >> 16) & 1u);   // RTNE
  return (unsigned short)(v >> 16);
}

// pack two f32 -> one dword of 2 bf16 (lo=a, hi=b), RTNE
__device__ inline unsigned cvt_pk_bf16(float a, float b) {
  unsigned r;
  asm("v_cvt_pk_bf16_f32 %0, %1, %2" : "=v"(r) : "v"(a), "v"(b));
  return r;
}

// v_permlane16_swap_b32: a.lanes[16..31] <-> b.lanes[0..15] (per 32-lane half)
__device__ inline void permlane16_swap_rw(unsigned &a, unsigned &b) {
  asm("v_permlane16_swap_b32 %0, %1" : "+v"(a), "+v"(b));
}

// async global->LDS, 16B/lane; LDS dest = wave-uniform base + lane*16.
__device__ inline void async16(const unsigned short* g, unsigned short* l) {
  __builtin_amdgcn_global_load_lds(
      (const __attribute__((address_space(1))) unsigned int*)g,
      (__attribute__((address_space(3))) unsigned int*)l, 16, 0, 0);
}

// ---- prep: W transposes (+cvt) and optional X cvt, ONE launch ----
__global__ __launch_bounds__(256) void prep_kernel(
    const float* __restrict__ X, const float* __restrict__ Wqkv,
    const float* __restrict__ Wout, unsigned short* __restrict__ Xb,
    unsigned short* __restrict__ Wqkvt, unsigned short* __restrict__ Woutt) {
  const int j = blockIdx.x, t = threadIdx.x;
  if (j >= 4096) {
    int i = ((j - 4096) * 256 + t) * 8;
    float4 a = *(const float4*)&X[i];
    float4 b = *(const float4*)&X[i + 4];
    short8 o;
    o[0] = (short)f2bf(a.x); o[1] = (short)f2bf(a.y);
    o[2] = (short)f2bf(a.z); o[3] = (short)f2bf(a.w);
    o[4] = (short)f2bf(b.x); o[5] = (short)f2bf(b.y);
    o[6] = (short)f2bf(b.z); o[7] = (short)f2bf(b.w);
    *(short8*)&Xb[i] = o;
    return;
  }
  __shared__ unsigned short tile[32][33];
  const float* in; unsigned short* out; int N, tn, tk;
  if (j < 3072) { in = Wqkv; out = Wqkvt; N = 3072; tn = j % 96; tk = j / 96; }
  else { int u = j - 3072; in = Wout; out = Woutt; N = 1024; tn = u & 31; tk = u >> 5; }
  const int n0 = tn * 32, k0 = tk * 32;
  const int tx = t & 31, ty = t >> 5;   // 32 x 8
#pragma unroll
  for (int i = 0; i < 32; i += 8)
    tile[ty + i][tx] = f2bf(in[(size_t)(k0 + ty + i) * N + n0 + tx]);
  __syncthreads();
#pragma unroll
  for (int i = 0; i < 32; i += 8)
    out[(size_t)(n0 + ty + i) * 1024 + k0 + tx] = tile[tx][ty + i];
}

// ===== 128x128-tile MFMA GEMM core, 2-phase LDS double-buffer (T3 minimum) =====
// STAGE(t+1) issued BEFORE compute(t); ONE barrier per K-iter (was 2).
// Load latency hides under the MFMA cluster; barrier's vmcnt drain is cheap
// because the loads had a full compute phase to land.
#define GEMM128_BODY(APTR, BPTR)                                                   \
  __shared__ __align__(16) unsigned short As[2][128][64];                          \
  __shared__ __align__(16) unsigned short Bs[2][128][64];                          \
  const int m0 = blockIdx.y * 128, n0 = blockIdx.x * 128;                          \
  const int t = threadIdx.x, lane = t & 63, wave = t >> 6;                         \
  const int quad = lane >> 4, l16 = lane & 15;                                     \
  const int wm = (wave >> 1) * 64, wn = (wave & 1) * 64;                           \
  const int lr = lane >> 3, lc = lane & 7, sc8 = (lc ^ lr) * 8;                    \
  const int sw = l16 & 7;                                                          \
  const int pA0 = (quad ^ sw) * 8, pA1 = ((4 + quad) ^ sw) * 8;                    \
  floatx4 acc[4][4];                                                               \
  _Pragma("unroll") for (int mi = 0; mi < 4; mi++)                                 \
      _Pragma("unroll") for (int ni = 0; ni < 4; ni++)                             \
          acc[mi][ni] = (floatx4){0.f, 0.f, 0.f, 0.f};                             \
  _Pragma("unroll") for (int i = 0; i < 4; i++) {                                  \
    int rb = wave * 32 + i * 8;                                                    \
    async16(&APTR[(size_t)(m0 + rb + lr) * DIM + sc8], &As[0][rb][0]);             \
    async16(&BPTR[(size_t)(n0 + rb + lr) * DIM + sc8], &Bs[0][rb][0]);             \
  }                                                                                \
  __syncthreads();                                                                 \
  for (int kt = 0; kt < DIM / 64; ++kt) {                                          \
    const int cur = kt & 1;                                                        \
    if (kt + 1 < DIM / 64) {                                                       \
      const int k1 = (kt + 1) * 64;                                                \
      _Pragma("unroll") for (int i = 0; i < 4; i++) {                              \
        int rb = wave * 32 + i * 8;                                                \
        async16(&APTR[(size_t)(m0 + rb + lr) * DIM + k1 + sc8], &As[cur ^ 1][rb][0]); \
        async16(&BPTR[(size_t)(n0 + rb + lr) * DIM + k1 + sc8], &Bs[cur ^ 1][rb][0]); \
      }                                                                            \
    }                                                                              \
    short8 a0[4], a1[4];                                                           \
    _Pragma("unroll") for (int mi = 0; mi < 4; mi++) {                             \
      int row = wm + mi * 16 + l16;                                                \
      a0[mi] = *(const short8*)&As[cur][row][pA0];                                 \
      a1[mi] = *(const short8*)&As[cur][row][pA1];                                 \
    }                                                                              \
    _Pragma("unroll") for (int ni = 0; ni < 4; ni++) {                             \
      int row = wn + ni * 16 + l16;                                                \
      short8 b0 = *(const short8*)&Bs[cur][row][pA0];                              \
      short8 b1 = *(const short8*)&Bs[cur][row][pA1];                              \
      _Pragma("unroll") for (int mi = 0; mi < 4; mi++) {                           \
        acc[mi][ni] = __builtin_amdgcn_mfma_f32_16x16x32_bf16(a0[mi], b0, acc[mi][ni], 0, 0, 0); \
        acc[mi][ni] = __builtin_amdgcn_mfma_f32_16x16x32_bf16(a1[mi], b1, acc[mi][ni], 0, 0, 0); \
      }                                                                            \
    }                                                                              \
    __syncthreads();                                                               \
  }

// ---- GEMM1: qkv = Xb @ Wqkvt^T + b; scatter Q^T(prescaled)/K/V^T ----
__global__ __launch_bounds__(256) void gemm_qkv128(
    const unsigned short* __restrict__ Xb,
    const unsigned short* __restrict__ Wt,
    const float* __restrict__ bias,
    unsigned short* __restrict__ Qgt,
    unsigned short* __restrict__ Kg,
    unsigned short* __restrict__ Vgt) {
  GEMM128_BODY(Xb, Wt)
  const int section = n0 >> 10;
  const int head = ((n0 + wn) >> 6) & 15;
#pragma unroll
  for (int mi = 0; mi < 4; mi++) {
    int mg = m0 + wm + mi * 16 + quad * 4;
    int bb = mg >> 11, sb = mg & 2047;
    size_t y = (size_t)bb * NHEAD + head;
    if (section == 2) {
#pragma unroll
      for (int ni = 0; ni < 4; ni++) {
        int hdi = ni * 16 + l16;
        float bv = bias[n0 + wn + hdi];
        ushort4v o;
#pragma unroll
        for (int r = 0; r < 4; r++) o[r] = f2bf(acc[mi][ni][r] + bv);
        *(ushort4v*)&Vgt[(y * HDIM + hdi) * S_LEN + sb] = o;
      }
    } else if (section == 0) {
#pragma unroll
      for (int ni = 0; ni < 4; ni++) {
        int hdi = ni * 16 + l16;
        float bv = bias[n0 + wn + hdi];
        ushort4v o;
#pragma unroll
        for (int r = 0; r < 4; r++) o[r] = f2bf((acc[mi][ni][r] + bv) * Q_PRESCALE);
        *(ushort4v*)&Qgt[(y * HDIM + hdi) * S_LEN + sb] = o;
      }
    } else {
#pragma unroll
      for (int ni = 0; ni < 4; ni++) {
        int hdi = ni * 16 + l16;
        float bv = bias[n0 + wn + hdi];
#pragma unroll
        for (int r = 0; r < 4; r++)
          Kg[(y * S_LEN + sb + r) * HDIM + hdi] = f2bf(acc[mi][ni][r] + bv);
      }
    }
  }
}

// ---- GEMM2: out = attnB @ Woutt^T + b (fp32 out), 64x64 tile, 2-phase dbuf ----
__global__ __launch_bounds__(128) void gemm_out64(
    const unsigned short* __restrict__ A,
    const unsigned short* __restrict__ Wt,
    const float* __restrict__ bias,
    float* __restrict__ outp) {
  __shared__ __align__(16) unsigned short As[2][64][64];
  __shared__ __align__(16) unsigned short Bs[2][64][64];
  const int m0 = blockIdx.y * 64, n0 = blockIdx.x * 64;
  const int t = threadIdx.x, lane = t & 63, wave = t >> 6;   // wave 0..1
  const int quad = lane >> 4, l16 = lane & 15;
  const int wn = wave * 32;
  const int lr = lane >> 3, lc = lane & 7, sc8 = (lc ^ lr) * 8;
  const int sw = l16 & 7;
  const int pA0 = (quad ^ sw) * 8, pA1 = ((4 + quad) ^ sw) * 8;
  floatx4 acc[4][2];
#pragma unroll
  for (int mi = 0; mi < 4; mi++)
#pragma unroll
    for (int ni = 0; ni < 2; ni++) acc[mi][ni] = (floatx4){0.f, 0.f, 0.f, 0.f};

#pragma unroll
  for (int i = 0; i < 4; i++) {
    int rb = wave * 32 + i * 8;
    async16(&A[(size_t)(m0 + rb + lr) * DIM + sc8], &As[0][rb][0]);
    async16(&Wt[(size_t)(n0 + rb + lr) * DIM + sc8], &Bs[0][rb][0]);
  }
  __syncthreads();
  for (int kt = 0; kt < DIM / 64; ++kt) {
    const int cur = kt & 1;
    if (kt + 1 < DIM / 64) {
      const int k1 = (kt + 1) * 64;
#pragma unroll
      for (int i = 0; i < 4; i++) {
        int rb = wave * 32 + i * 8;
        async16(&A[(size_t)(m0 + rb + lr) * DIM + k1 + sc8], &As[cur ^ 1][rb][0]);
        async16(&Wt[(size_t)(n0 + rb + lr) * DIM + k1 + sc8], &Bs[cur ^ 1][rb][0]);
      }
    }
    short8 a0[4], a1[4];
#pragma unroll
    for (int mi = 0; mi < 4; mi++) {
      int row = mi * 16 + l16;
      a0[mi] = *(const short8*)&As[cur][row][pA0];
      a1[mi] = *(const short8*)&As[cur][row][pA1];
    }
#pragma unroll
    for (int ni = 0; ni < 2; ni++) {
      int row = wn + ni * 16 + l16;
      short8 b0 = *(const short8*)&Bs[cur][row][pA0];
      short8 b1 = *(const short8*)&Bs[cur][row][pA1];
#pragma unroll
      for (int mi = 0; mi < 4; mi++) {
        acc[mi][ni] = __builtin_amdgcn_mfma_f32_16x16x32_bf16(a0[mi], b0, acc[mi][ni], 0, 0, 0);
        acc[mi][ni] = __builtin_amdgcn_mfma_f32_16x16x32_bf16(a1[mi], b1, acc[mi][ni], 0, 0, 0);
      }
    }
    __syncthreads();
  }
#pragma unroll
  for (int ni = 0; ni < 2; ni++) {
    int n = n0 + wn + ni * 16 + l16;
    float bv = bias[n];
#pragma unroll
    for (int mi = 0; mi < 4; mi++) {
      int mg = m0 + mi * 16 + quad * 4;
#pragma unroll
      for (int r = 0; r < 4; r++)
        outp[(size_t)(mg + r) * DIM + n] = acc[mi][ni][r] + bv;
    }
  }
}

// ---- fallback GEMM1 (64-tile, inline X convert) for ws_size < 48 MiB ----
__global__ __launch_bounds__(256) void gemm_qkv_kernel(
    const float* __restrict__ X,
    const unsigned short* __restrict__ Wt,
    const float* __restrict__ bias,
    unsigned short* __restrict__ Qgt,
    unsigned short* __restrict__ Kg,
    unsigned short* __restrict__ Vgt,
    int g0, int G) {
  __shared__ __align__(16) unsigned short As[64][72];
  __shared__ __align__(16) unsigned short Bs[64][72];
  const int tn = blockIdx.x;
  const int section = tn / G, within = tn % G;
  const int n0 = section * 1024 + (g0 + within) * 64;
  const int m0 = blockIdx.y * 64;
  const int t = threadIdx.x, lane = t & 63, wave = t >> 6;
  const int quad = lane >> 4, l16 = lane & 15;

  floatx4 acc[4];
#pragma unroll
  for (int i = 0; i < 4; i++) acc[i] = (floatx4){0.f, 0.f, 0.f, 0.f};

  for (int k0 = 0; k0 < DIM; k0 += 64) {
#pragma unroll
    for (int i = 0; i < 2; i++) {
      int v = t + i * 256;
      int row = v >> 3, cc = (v & 7) * 8;
      float4 f0 = *(const float4*)&X[(size_t)(m0 + row) * DIM + k0 + cc];
      float4 f1 = *(const float4*)&X[(size_t)(m0 + row) * DIM + k0 + cc + 4];
      short8 o;
      o[0] = (short)f2bf(f0.x); o[1] = (short)f2bf(f0.y);
      o[2] = (short)f2bf(f0.z); o[3] = (short)f2bf(f0.w);
      o[4] = (short)f2bf(f1.x); o[5] = (short)f2bf(f1.y);
      o[6] = (short)f2bf(f1.z); o[7] = (short)f2bf(f1.w);
      *(short8*)&As[row][cc] = o;
      *(short8*)&Bs[row][cc] = *(const short8*)&Wt[(size_t)(n0 + row) * DIM + k0 + cc];
    }
    __syncthreads();
    short8 a0 = *(const short8*)&As[wave * 16 + l16][quad * 8];
    short8 a1 = *(const short8*)&As[wave * 16 + l16][32 + quad * 8];
#pragma unroll
    for (int nt = 0; nt < 4; nt++) {
      short8 b0 = *(const short8*)&Bs[nt * 16 + l16][quad * 8];
      short8 b1 = *(const short8*)&Bs[nt * 16 + l16][32 + quad * 8];
      acc[nt] = __builtin_amdgcn_mfma_f32_16x16x32_bf16(a0, b0, acc[nt], 0, 0, 0);
      acc[nt] = __builtin_amdgcn_mfma_f32_16x16x32_bf16(a1, b1, acc[nt], 0, 0, 0);
    }
    __syncthreads();
  }

  const int mbase = m0 + wave * 16 + quad * 4;
  const int b = mbase >> 11, sbase = mbase & 2047;
  const int y = b * G + within;
  if (section == 2) {
#pragma unroll
    for (int nt = 0; nt < 4; nt++) {
      int hdi = nt * 16 + l16;
      float bv = bias[n0 + hdi];
      ushort4v o;
#pragma unroll
      for (int r = 0; r < 4; r++) o[r] = f2bf(acc[nt][r] + bv);
      *(ushort4v*)&Vgt[((size_t)y * HDIM + hdi) * S_LEN + sbase] = o;
    }
  } else if (section == 0) {
#pragma unroll
    for (int nt = 0; nt < 4; nt++) {
      int hdi = nt * 16 + l16;
      float bv = bias[n0 + hdi];
      ushort4v o;
#pragma unroll
      for (int r = 0; r < 4; r++) o[r] = f2bf((acc[nt][r] + bv) * Q_PRESCALE);
      *(ushort4v*)&Qgt[((size_t)y * HDIM + hdi) * S_LEN + sbase] = o;
    }
  } else {
#pragma unroll
    for (int nt = 0; nt < 4; nt++) {
      int hdi = nt * 16 + l16;
      float bv = bias[n0 + hdi];
#pragma unroll
      for (int r = 0; r < 4; r++)
        Kg[((size_t)y * S_LEN + sbase + r) * HDIM + hdi] = f2bf(acc[nt][r] + bv);
    }
  }
}

// ---- attention v10: swapped-QK^T + permlane net + T15 2-deep PV pipeline ----
__global__ __launch_bounds__(256) void attn_kernel(
    const unsigned short* __restrict__ Qgt,
    const unsigned short* __restrict__ Kg,
    const unsigned short* __restrict__ Vgt,
    unsigned short* __restrict__ attnB) {
  __shared__ __align__(16) unsigned short Ks[2][64][64];   // [buf][key][hd], XOR-swizzled
  __shared__ __align__(16) unsigned short Vs[3][64][64];   // [slot][hd][key], XOR-swizzled

  const int y = blockIdx.x;                // 0..31 (b,h)
  const int b = y >> 4, h = y & 15;
  const int qt = 31 - blockIdx.y;          // heavy-first
  const int q0 = qt * 64;
  const int nT = qt + 1;
  const int t = threadIdx.x;
  const int lane = t & 63, wave = t >> 6;
  const int quad = lane >> 4, l16 = lane & 15;
  const int lr = lane >> 3, lc = lane & 7;
  const int sc8 = (lc ^ lr) * 8;
  const int sw = l16 & 7;
  const int p0 = (quad ^ sw) * 8, p1 = ((4 + quad) ^ sw) * 8;

  const unsigned short* Qh = Qgt + (size_t)y * S_LEN * HDIM;   // [hd][s]
  const unsigned short* Kh = Kg + (size_t)y * S_LEN * HDIM;    // [s][hd]
  const unsigned short* Vh = Vgt + (size_t)y * HDIM * S_LEN;   // [hd][s]

  // constant Ones B-fragment: B[n][k] = (n==0) ? 1 : 0  -> row-sum in col 0
  const unsigned ov = (l16 == 0) ? 0x3F803F80u : 0u;
  const uintx4 ou = {ov, ov, ov, ov};
  const short8 ones = __builtin_bit_cast(short8, ou);

  // Q fragment from transposed layout: aq0[j] = Q[hd=quad*8+j][s=q0+wave*16+l16]
  short8 aq0, aq1;
  {
    const int s = q0 + wave * 16 + l16;
#pragma unroll
    for (int j = 0; j < 8; j++) {
      aq0[j] = (short)Qh[(size_t)(quad * 8 + j) * S_LEN + s];
      aq1[j] = (short)Qh[(size_t)(32 + quad * 8 + j) * S_LEN + s];
    }
  }

  floatx4 o_acc[5];
#pragma unroll
  for (int dt = 0; dt < 5; dt++) o_acc[dt] = (floatx4){0.f, 0.f, 0.f, 0.f};

  {
    int rb = wave * 16;
#pragma unroll
    for (int i = 0; i < 2; i++) {
      async16(&Kh[(size_t)(rb + i * 8 + lr) * HDIM + sc8], &Ks[0][rb + i * 8][0]);
      async16(&Vh[(size_t)(rb + i * 8 + lr) * S_LEN + sc8], &Vs[0][rb + i * 8][0]);
    }
  }

  int prevV = 2, curV = 0, nextV = 1;
  short8 apP0, apP1;                       // P frags of tile t-1

  for (int tt = 0; tt < nT; tt++) {
    const int j0 = tt * 64;
    const int kb = tt & 1;
    __syncthreads();
    if (tt + 1 < nT) {
      int j1 = j0 + 64;
      int rb = wave * 16;
#pragma unroll
      for (int i = 0; i < 2; i++) {
        async16(&Kh[(size_t)(j1 + rb + i * 8 + lr) * HDIM + sc8], &Ks[kb ^ 1][rb + i * 8][0]);
        async16(&Vh[(size_t)(rb + i * 8 + lr) * S_LEN + j1 + sc8], &Vs[nextV][rb + i * 8][0]);
      }
    }

    // swapped QK^T: sc[nt][r] = S[key = j0 + nt*16 + quad*4 + r][q = q0 + wave*16 + l16]
    floatx4 sc[4];
#pragma unroll
    for (int nt = 0; nt < 4; nt++) {
      short8 kb0 = *(const short8*)&Ks[kb][nt * 16 + l16][p0];
      short8 kb1 = *(const short8*)&Ks[kb][nt * 16 + l16][p1];
      sc[nt] = (floatx4){0.f, 0.f, 0.f, 0.f};
      sc[nt] = __builtin_amdgcn_mfma_f32_16x16x32_bf16(kb0, aq0, sc[nt], 0, 0, 0);
      sc[nt] = __builtin_amdgcn_mfma_f32_16x16x32_bf16(kb1, aq1, sc[nt], 0, 0, 0);
    }

    // PV(t-1): independent of sc -> overlaps the softmax below on the MFMA pipe
    if (tt > 0) {
#pragma unroll
      for (int dt = 0; dt < 5; dt++) {
        short8 vb0 = (dt < 4) ? *(const short8*)&Vs[prevV][dt * 16 + l16][p0] : ones;
        short8 vb1 = (dt < 4) ? *(const short8*)&Vs[prevV][dt * 16 + l16][p1] : ones;
        o_acc[dt] = __builtin_amdgcn_mfma_f32_16x16x32_bf16(apP0, vb0, o_acc[dt], 0, 0, 0);
        o_acc[dt] = __builtin_amdgcn_mfma_f32_16x16x32_bf16(apP1, vb1, o_acc[dt], 0, 0, 0);
      }
    }

    float p[4][4];
#pragma unroll
    for (int nt = 0; nt < 4; nt++)
#pragma unroll
      for (int r = 0; r < 4; r++)
        p[nt][r] = exp2f(sc[nt][r]);
    if (j0 == q0) {
      const int ql = wave * 16 + l16;
#pragma unroll
      for (int nt = 0; nt < 4; nt++)
#pragma unroll
        for (int r = 0; r < 4; r++)
          if (nt * 16 + quad * 4 + r > ql) p[nt][r] = 0.f;
    }

    // pack r-pairs to bf16 dwords
    unsigned pk00 = cvt_pk_bf16(p[0][0], p[0][1]), pk01 = cvt_pk_bf16(p[0][2], p[0][3]);
    unsigned pk10 = cvt_pk_bf16(p[1][0], p[1][1]), pk11 = cvt_pk_bf16(p[1][2], p[1][3]);
    unsigned pk20 = cvt_pk_bf16(p[2][0], p[2][1]), pk21 = cvt_pk_bf16(p[2][2], p[2][3]);
    unsigned pk30 = cvt_pk_bf16(p[3][0], p[3][1]), pk31 = cvt_pk_bf16(p[3][2], p[3][3]);

    // permlane network -> P frags for NEXT iteration's PV
    auto sa0 = __builtin_amdgcn_permlane32_swap(pk00, pk10, false, false);
    auto sa1 = __builtin_amdgcn_permlane32_swap(pk01, pk11, false, false);
    auto sb0 = __builtin_amdgcn_permlane32_swap(pk20, pk30, false, false);
    auto sb1 = __builtin_amdgcn_permlane32_swap(pk21, pk31, false, false);
    unsigned xa0 = (unsigned)sa0[0], ya0 = (unsigned)sa0[1];
    unsigned xa1 = (unsigned)sa1[0], ya1 = (unsigned)sa1[1];
    unsigned xb0 = (unsigned)sb0[0], yb0 = (unsigned)sb0[1];
    unsigned xb1 = (unsigned)sb1[0], yb1 = (unsigned)sb1[1];
    permlane16_swap_rw(xa0, ya0);
    permlane16_swap_rw(xa1, ya1);
    permlane16_swap_rw(xb0, yb0);
    permlane16_swap_rw(xb1, yb1);
    uintx4 u0 = {xa0, xa1, ya0, ya1};
    apP0 = __builtin_bit_cast(short8, u0);
    uintx4 u1 = {xb0, xb1, yb0, yb1};
    apP1 = __builtin_bit_cast(short8, u1);

    int tmp = prevV; prevV = curV; curV = nextV; nextV = tmp;
  }

  // epilogue: PV(nT-1) from Vs[prevV] (= (nT-1)%3)
#pragma unroll
  for (int dt = 0; dt < 5; dt++) {
    short8 vb0 = (dt < 4) ? *(const short8*)&Vs[prevV][dt * 16 + l16][p0] : ones;
    short8 vb1 = (dt < 4) ? *(const short8*)&Vs[prevV][dt * 16 + l16][p1] : ones;
    o_acc[dt] = __builtin_amdgcn_mfma_f32_16x16x32_bf16(apP0, vb0, o_acc[dt], 0, 0, 0);
    o_acc[dt] = __builtin_amdgcn_mfma_f32_16x16x32_bf16(apP1, vb1, o_acc[dt], 0, 0, 0);
  }

  float linv[4];
#pragma unroll
  for (int r = 0; r < 4; r++)
    linv[r] = 1.0f / __shfl(o_acc[4][r], quad << 4);
#pragma unroll
  for (int dt = 0; dt < 4; dt++)
#pragma unroll
    for (int r = 0; r < 4; r++) {
      int qg = q0 + wave * 16 + quad * 4 + r;
      attnB[(size_t)(b * S_LEN + qg) * DIM + h * HDIM + dt * 16 + l16] =
          f2bf(o_acc[dt][r] * linv[r]);
    }
}

extern "C" void kernel_launch(void* const* d_in, const int* in_sizes, int n_in,
                              void* d_out, int out_size, void* d_ws, size_t ws_size,
                              hipStream_t stream) {
  const float* X    = (const float*)d_in[0];
  const float* Wqkv = (const float*)d_in[1];
  const float* bqkv = (const float*)d_in[2];
  const float* Wout = (const float*)d_in[3];
  const float* bout = (const float*)d_in[4];
  float* outp = (float*)d_out;

  unsigned short* Wqkvt = (unsigned short*)d_ws;
  unsigned short* Woutt = Wqkvt + (size_t)3145728;
  unsigned short* attnB = Woutt + (size_t)1048576;
  unsigned short* Qgt   = attnB + (size_t)4194304;
  unsigned short* Kg    = Qgt + (size_t)4194304;
  unsigned short* Vgt   = Kg + (size_t)4194304;
  unsigned short* Xb    = Vgt + (size_t)4194304;

  const bool bigWs = ws_size >= (size_t)48 * 1024 * 1024;

  if (bigWs) {
    // one prep launch: W transposes (blocks 0..4095) + X cvt (blocks 4096..6143)
    prep_kernel<<<6144, 256, 0, stream>>>(X, Wqkv, Wout, Xb, Wqkvt, Woutt);
    gemm_qkv128<<<dim3(24, 32), 256, 0, stream>>>(Xb, Wqkvt, bqkv, Qgt, Kg, Vgt);
  } else {
    // transposes only (no Xb room); 64-tile gemm converts X inline
    prep_kernel<<<4096, 256, 0, stream>>>(X, Wqkv, Wout, nullptr, Wqkvt, Woutt);
    gemm_qkv_kernel<<<dim3(48, 64), 256, 0, stream>>>(
        X, Wqkvt, bqkv, Qgt, Kg, Vgt, 0, 16);
  }
  attn_kernel<<<dim3(32, 32), 256, 0, stream>>>(Qgt, Kg, Vgt, attnB);
  gemm_out64<<<dim3(16, 64), 128, 0, stream>>>(attnB, Woutt, bout, outp);
}